// Round 6
// baseline (672.825 us; speedup 1.0000x reference)
//
#include <hip/hip_runtime.h>
#include <hip/hip_bf16.h>

typedef float f32x4 __attribute__((ext_vector_type(4)));
typedef float f32x16 __attribute__((ext_vector_type(16)));
typedef short s16x8 __attribute__((ext_vector_type(8)));
typedef int i32x4 __attribute__((ext_vector_type(4)));
typedef unsigned short u16;

__constant__ float NF4_TBL[16] = {
    -1.0f, -0.6961928009986877f, -0.5250730514526367f, -0.39491748809814453f,
    -0.28444138169288635f, -0.18477343022823334f, -0.09105003625154495f, 0.0f,
    0.07958029955625534f, 0.16093020141124725f, 0.24611230194568634f,
    0.33791524171829224f, 0.44070982933044434f, 0.5626170039176941f,
    0.7229568362236023f, 1.0f};

static __device__ __forceinline__ unsigned short f2bf(float f) {
  unsigned u = __builtin_bit_cast(unsigned, f);
  u += 0x7fffu + ((u >> 16) & 1u);  // RNE
  return (unsigned short)(u >> 16);
}

static __device__ __forceinline__ void gload16(const void* g, void* l) {
  __builtin_amdgcn_global_load_lds(
      (const __attribute__((address_space(1))) unsigned*)g,
      (__attribute__((address_space(3))) unsigned*)l, 16, 0, 0);
}

// ---------------- fused prep: X fp32->bf16 and NF4 W->bf16 ----------------
__global__ __launch_bounds__(256)
void prep(const float* __restrict__ x, const int* __restrict__ codes,
          const float* __restrict__ absmax, u16* __restrict__ xb,
          u16* __restrict__ wb, long long nx, long long nk) {
  __shared__ float lut[512];
  for (int j = threadIdx.x; j < 512; j += 256) lut[j] = NF4_TBL[j >> 5];
  __syncthreads();
  long long i = ((long long)blockIdx.x * 256 + threadIdx.x) * 8;
  if (i < nx) {
    f32x4 a = *(const f32x4*)(x + i);
    f32x4 b = *(const f32x4*)(x + i + 4);
    s16x8 o;
#pragma unroll
    for (int j = 0; j < 4; ++j) {
      o[j] = (short)f2bf(a[j]);
      o[j + 4] = (short)f2bf(b[j]);
    }
    *(s16x8*)(xb + i) = o;
  } else {
    long long e = i - nx;
    if (e < nk) {
      const int ln31 = threadIdx.x & 31;
      i32x4 c0 = *(const i32x4*)(codes + e);
      i32x4 c1 = *(const i32x4*)(codes + e + 4);
      float am = absmax[e >> 6];
      s16x8 o;
#pragma unroll
      for (int j = 0; j < 4; ++j) {
        o[j] = (short)f2bf(lut[(c0[j] << 5) + ln31] * am);
        o[j + 4] = (short)f2bf(lut[(c1[j] << 5) + ln31] * am);
      }
      *(s16x8*)(wb + e) = o;
    }
  }
}

// standalone dequant for the mid fallback path
__global__ __launch_bounds__(256)
void dequant_w(const int* __restrict__ codes, const float* __restrict__ absmax,
               u16* __restrict__ wq, long long total) {
  __shared__ float lut[512];
  for (int j = threadIdx.x; j < 512; j += 256) lut[j] = NF4_TBL[j >> 5];
  __syncthreads();
  const int ln31 = threadIdx.x & 31;
  long long e = ((long long)blockIdx.x * 256 + threadIdx.x) * 8;
  if (e >= total) return;
  i32x4 c0 = *(const i32x4*)(codes + e);
  i32x4 c1 = *(const i32x4*)(codes + e + 4);
  float am = absmax[e >> 6];
  s16x8 o;
#pragma unroll
  for (int j = 0; j < 4; ++j) {
    o[j] = (short)f2bf(lut[(c0[j] << 5) + ln31] * am);
    o[j + 4] = (short)f2bf(lut[(c1[j] << 5) + ln31] * am);
  }
  *(s16x8*)(wq + e) = o;
}

// ===== main: 256x256 bf16 GEMM, BK=64, 8-phase, 32x32x16, READ-AHEAD =====
// Round-6 change: fragment ds_reads for phase p+1 are issued inside phase p,
// right after p's lgkmcnt(0) and BEFORE p's MFMA cluster, into ping-ponged
// fragment registers. The reads drain in the MFMA+barrier shadow, so the
// lgkmcnt(0) at p+1 is (nearly) free and LDS-read time no longer adds to
// MFMA time inside the two-barrier phase.
// Legality vs the vmcnt ring (verified per phase): every region read at p+1
// was staged >=4 phases earlier and its gloads are drained by the VM6 that
// precedes the read issue (p8-reads: p8's VM6; p5-reads: p4's VM6; p7-reads
// staged at p1, drained at p4's VM6). Frag-reg WAR: >=2 barrier-separated
// phases between last MFMA use and re-read issue for every set.
#define VM6() asm volatile("s_waitcnt vmcnt(6)" ::: "memory")
#define VM0() asm volatile("s_waitcnt vmcnt(0)" ::: "memory")
#define SB0() __builtin_amdgcn_sched_barrier(0)
#define SYNC_IN()                                            \
  do {                                                       \
    __builtin_amdgcn_s_barrier();                            \
    asm volatile("s_waitcnt lgkmcnt(0)" ::: "memory");       \
    __builtin_amdgcn_sched_barrier(0);                       \
  } while (0)
#define SYNC_OUT()                                           \
  do {                                                       \
    __builtin_amdgcn_s_barrier();                            \
    __builtin_amdgcn_sched_barrier(0);                       \
  } while (0)

// one phase's MFMA cluster: 2 m-tiles x 4 k-steps into acc[MB..MB+1][NB]
#define MM32(AV, BV, MB, NB)                                               \
  do {                                                                     \
    __builtin_amdgcn_s_setprio(1);                                         \
    _Pragma("unroll") for (int s_ = 0; s_ < 4; ++s_)                       \
    _Pragma("unroll") for (int mp_ = 0; mp_ < 2; ++mp_)                    \
        acc[(MB) + mp_][NB] = __builtin_amdgcn_mfma_f32_32x32x16_bf16(     \
            AV[mp_][s_], BV[s_], acc[(MB) + mp_][NB], 0, 0, 0);            \
    __builtin_amdgcn_s_setprio(0);                                         \
  } while (0)

__global__ __launch_bounds__(512, 2)
void gemm32(const u16* __restrict__ A, const u16* __restrict__ B,
            const float* __restrict__ BIAS, float* __restrict__ OUT,
            int M, int N, int K) {
  __shared__ __align__(16) char lds[131072];  // 2 buf x (A 32K + B 32K)

  const int tid = threadIdx.x;
  const int lane = tid & 63;
  const int wid = tid >> 6;
  const int wr = wid >> 2;  // 0..1 : M-half (128 rows)
  const int wc = wid & 3;   // 0..3 : N-quarter (64 cols)

  int nwg = (int)gridDim.x;
  int b = (int)blockIdx.x;
  if ((nwg & 7) == 0) b = (b & 7) * (nwg >> 3) + (b >> 3);  // XCD swizzle
  const int ntm = M / 256;
  const int tn = b / ntm;  // column-major tile order: B-panel L2 reuse
  const int tm = b % ntm;

  const long long K2 = (long long)K * 2;
  // ---- staging source (pre-swizzled 16B slot within 128B K-row) ----
  const int trow = tid >> 3;
  const int skey = (trow & 7) ^ ((trow >> 3) & 3);
  const int scol = ((tid & 7) ^ skey) << 4;
  const char* sgA =
      (const char*)A + ((long long)tm * 256 + trow) * K2 + scol;
  const char* sgB = (const char*)B +
                    ((long long)tn * 256 + (tid >> 8) * 64 + (trow & 31)) * K2 +
                    scol;
  const int sldso = tid * 16;

  // stage one half-tile (2 x gload16)
  auto stA = [&](int kt, int buf, int h) {
    char* d = lds + buf * 65536 + h * 16384 + sldso;
    const char* s = sgA + (long long)h * 64 * K2 + (long long)kt * 128;
    gload16(s, d);
    gload16(s + 128 * K2, d + 8192);
  };
  auto stB = [&](int kt, int buf, int h) {
    char* d = lds + buf * 65536 + 32768 + h * 16384 + sldso;
    const char* s = sgB + (long long)h * 32 * K2 + (long long)kt * 128;
    gload16(s, d);
    gload16(s + 128 * K2, d + 8192);
  };

  // ---- fragment read addressing (32x32x16: A row=lane&31, k=(lane>>5)*8+j)
  const int l31 = lane & 31;
  const int lk = lane >> 5;
  const int rkey = (l31 & 7) ^ ((l31 >> 3) & 3);
  int aslot[4];
#pragma unroll
  for (int s_ = 0; s_ < 4; ++s_) aslot[s_] = ((s_ * 2 + lk) ^ rkey) << 4;

  // ping-ponged fragment sets (read-ahead-by-1)
  s16x8 aaE[2][4], aaO[2][4];          // A frags: h0-slot / h1-slot
  s16x8 bnA[4], bnB[4], bnC[4], bnD[4];  // B frags per (tile-parity, half)

  auto rdA32 = [&](int buf, int h, s16x8(&dst)[2][4]) {
    const char* p = lds + buf * 65536 + h * 16384 + (wr * 64 + l31) * 128;
#pragma unroll
    for (int mp_ = 0; mp_ < 2; ++mp_)
#pragma unroll
      for (int s_ = 0; s_ < 4; ++s_)
        dst[mp_][s_] = *(const s16x8*)(p + mp_ * 4096 + aslot[s_]);
  };
  auto rdB32 = [&](int buf, int h, s16x8(&bv)[4]) {
    const char* p =
        lds + buf * 65536 + 32768 + h * 16384 + (wc * 32 + l31) * 128;
#pragma unroll
    for (int s_ = 0; s_ < 4; ++s_) bv[s_] = *(const s16x8*)(p + aslot[s_]);
  };

  f32x16 acc[4][2];
  {
    f32x16 zz;
#pragma unroll
    for (int r = 0; r < 16; ++r) zz[r] = 0.f;
#pragma unroll
    for (int m_ = 0; m_ < 4; ++m_)
#pragma unroll
      for (int n_ = 0; n_ < 2; ++n_) acc[m_][n_] = zz;
  }

  const int nkt = K / 64;
  const int nit = nkt / 2;

  // prologue: buf0 <- kt0 (full), buf1 <- kt1 (all but A-half-1)
  stB(0, 0, 0);
  stA(0, 0, 0);
  stB(0, 0, 1);
  stA(0, 0, 1);
  stB(1, 1, 0);
  stA(1, 1, 0);
  stB(1, 1, 1);
  VM6();  // buf0 complete; buf1's newest 3 stages may stay in flight
  __builtin_amdgcn_s_barrier();
  // first-iteration p1 fragments
  rdA32(0, 0, aaE);
  rdB32(0, 0, bnA);

  for (int it = 0; it < nit; ++it) {
    const int kt = 2 * it;
    const bool full = (it + 1 < nit);
    __builtin_amdgcn_sched_barrier(0);
    // ---- p1: MM(aaE,bnA -> acc[0,1][0]); issue p2 reads ----
    stA(kt + 1, 1, 1);  // buf1.A-h1 <- kt+1 (read at p7)
    SYNC_IN();
    rdB32(0, 1, bnB);
    SB0();
    MM32(aaE, bnA, 0, 0);
    SYNC_OUT();
    // ---- p2 ----
    if (full) stB(kt + 2, 0, 0);
    SYNC_IN();
    rdA32(0, 1, aaO);
    SB0();
    MM32(aaE, bnB, 0, 1);
    SYNC_OUT();
    // ---- p3 ----
    if (full) stA(kt + 2, 0, 0);
    SYNC_IN();
    SB0();
    MM32(aaO, bnB, 2, 1);
    SYNC_OUT();
    // ---- p4: vmcnt gate; issue p5 reads (buf1, gated by this VM6) ----
    if (full) {
      stB(kt + 2, 0, 1);
      VM6();
    } else {
      VM0();
    }
    SYNC_IN();
    rdA32(1, 0, aaE);
    rdB32(1, 0, bnC);
    SB0();
    MM32(aaO, bnA, 2, 0);
    SYNC_OUT();
    // ---- p5 ----
    if (full) stA(kt + 2, 0, 1);
    SYNC_IN();
    rdB32(1, 1, bnD);
    SB0();
    MM32(aaE, bnC, 0, 0);
    SYNC_OUT();
    // ---- p6 ----
    if (full) stB(kt + 3, 1, 0);
    SYNC_IN();
    rdA32(1, 1, aaO);
    SB0();
    MM32(aaE, bnD, 0, 1);
    SYNC_OUT();
    // ---- p7 ----
    if (full) stA(kt + 3, 1, 0);
    SYNC_IN();
    SB0();
    MM32(aaO, bnD, 2, 1);
    SYNC_OUT();
    // ---- p8: vmcnt gate; issue next-iter p1 reads (gated by this VM6) ----
    if (full) {
      stB(kt + 3, 1, 1);
      VM6();
    }
    SYNC_IN();
    if (full) {
      rdA32(0, 0, aaE);
      rdB32(0, 0, bnA);
    }
    SB0();
    MM32(aaO, bnC, 2, 0);
    SYNC_OUT();
  }

  // epilogue: 32x32 C/D layout col=lane&31, row=(r&3)+8*(r>>2)+4*(lane>>5)
  const int ocol = tn * 256 + wc * 64 + l31;
  const int orow0 = tm * 256 + wr * 128 + 4 * lk;
  const float bv0 = BIAS[ocol];
  const float bv1 = BIAS[ocol + 32];
#pragma unroll
  for (int m_ = 0; m_ < 4; ++m_)
#pragma unroll
    for (int n_ = 0; n_ < 2; ++n_) {
      const float bb = n_ ? bv1 : bv0;
      const long long cb = (long long)0 + ocol + n_ * 32;
#pragma unroll
      for (int r = 0; r < 16; ++r) {
        const int row = orow0 + m_ * 32 + (r & 3) + 8 * (r >> 2);
        OUT[(long long)row * N + cb] = acc[m_][n_][r] + bb;
      }
    }
}

// ---------------- fallback: 128x128 reg-staged kernel ----------------
#define BM 128
#define BN 128
#define BK 64

template <bool FUSED>
static __device__ __forceinline__ void stage_load(
    const float* __restrict__ ap0, const int* __restrict__ cp0,
    const u16* __restrict__ wp0, const float* __restrict__ am0, int K, int kt,
    f32x4 (&ar)[4][2], i32x4 (&cr)[4][2], s16x8 (&wreg)[4], float (&amr)[4]) {
  const size_t ko = (size_t)kt * BK;
#pragma unroll
  for (int p = 0; p < 4; ++p) {
    const float* ap = ap0 + (size_t)(p * 32) * K + ko;
    ar[p][0] = *(const f32x4*)ap;
    ar[p][1] = *(const f32x4*)(ap + 4);
    if constexpr (FUSED) {
      const int* cp = cp0 + (size_t)(p * 32) * K + ko;
      cr[p][0] = *(const i32x4*)cp;
      cr[p][1] = *(const i32x4*)(cp + 4);
      amr[p] = am0[p * 32 * (K >> 6) + kt];
    } else {
      wreg[p] = *(const s16x8*)(wp0 + (size_t)(p * 32) * K + ko);
    }
  }
}

template <bool FUSED>
__global__ __launch_bounds__(256, 2)
void gemm_nf4(const float* __restrict__ X, const int* __restrict__ CODES,
              const u16* __restrict__ WQ, const float* __restrict__ AMAX,
              const float* __restrict__ BIAS, float* __restrict__ OUT,
              int M, int N, int K) {
  __shared__ short As[BM * BK];
  __shared__ short Bs[BN * BK];
  __shared__ float lut[512];

  const int tid = threadIdx.x;
  const int lane = tid & 63;
  const int wid = tid >> 6;

  if constexpr (FUSED) {
#pragma unroll
    for (int j = 0; j < 2; ++j) {
      int idx = tid + j * 256;
      lut[idx] = NF4_TBL[idx >> 5];
    }
  }

  int nwg = (int)gridDim.x;
  int b = (int)blockIdx.x;
  if ((nwg & 7) == 0) b = (b & 7) * (nwg >> 3) + (b >> 3);
  const int ntn = N / BN;
  const int tm = b / ntn;
  const int tn = b % ntn;

  const int srow = tid >> 3;
  const int scol = (tid & 7) * 8;
  const int ln31 = tid & 31;
  const int swz_w = (srow & 7) << 4;

  const float* ap0 = X + (size_t)(tm * BM + srow) * K + scol;
  const int* cp0 = CODES + (size_t)(tn * BN + srow) * K + scol;
  const u16* wp0 = WQ + (size_t)(tn * BN + srow) * K + scol;
  const float* am0 = AMAX + (size_t)(tn * BN + srow) * (K >> 6);

  f32x4 ar[4][2];
  i32x4 cr[4][2];
  s16x8 wreg[4];
  float amr[4];

  f32x4 acc[4][4];
#pragma unroll
  for (int i = 0; i < 4; ++i)
#pragma unroll
    for (int j = 0; j < 4; ++j) {
      f32x4 z = {0.f, 0.f, 0.f, 0.f};
      acc[i][j] = z;
    }

  const int wr = wid >> 1;
  const int wc = wid & 1;
  const int frow = lane & 15;
  const int fcolb = (lane >> 4) * 16;
  const int arow = wr * 64 + frow;
  const int brow = wc * 64 + frow;
  const int aswz = (arow & 7) << 4;
  const int bswz = (brow & 7) << 4;
  const char* asp = (const char*)As + arow * 128;
  const char* bsp = (const char*)Bs + brow * 128;
  char* awp = (char*)As + srow * 128 + ((scol * 2) ^ swz_w);
  char* bwp = (char*)Bs + srow * 128 + ((scol * 2) ^ swz_w);

  const int nkt = K / BK;
  stage_load<FUSED>(ap0, cp0, wp0, am0, K, 0, ar, cr, wreg, amr);

  for (int kt = 0; kt < nkt; ++kt) {
    __syncthreads();
#pragma unroll
    for (int p = 0; p < 4; ++p) {
      s16x8 av;
#pragma unroll
      for (int j = 0; j < 4; ++j) {
        av[j] = (short)f2bf(ar[p][0][j]);
        av[j + 4] = (short)f2bf(ar[p][1][j]);
      }
      *(s16x8*)(awp + p * 32 * 128) = av;
      s16x8 bv;
      if constexpr (FUSED) {
        float am = amr[p];
#pragma unroll
        for (int j = 0; j < 4; ++j) {
          bv[j] = (short)f2bf(lut[(cr[p][0][j] << 5) + ln31] * am);
          bv[j + 4] = (short)f2bf(lut[(cr[p][1][j] << 5) + ln31] * am);
        }
      } else {
        bv = wreg[p];
      }
      *(s16x8*)(bwp + p * 32 * 128) = bv;
    }
    __syncthreads();

    if (kt + 1 < nkt)
      stage_load<FUSED>(ap0, cp0, wp0, am0, K, kt + 1, ar, cr, wreg, amr);

#pragma unroll
    for (int kk = 0; kk < 2; ++kk) {
      const int qa = (fcolb | (kk << 6)) ^ aswz;
      const int qb = (fcolb | (kk << 6)) ^ bswz;
      s16x8 afr[4], bfr[4];
#pragma unroll
      for (int mi = 0; mi < 4; ++mi)
        afr[mi] = *(const s16x8*)(asp + mi * 2048 + qa);
#pragma unroll
      for (int ni = 0; ni < 4; ++ni)
        bfr[ni] = *(const s16x8*)(bsp + ni * 2048 + qb);
#pragma unroll
      for (int mi = 0; mi < 4; ++mi)
#pragma unroll
        for (int ni = 0; ni < 4; ++ni)
          acc[mi][ni] = __builtin_amdgcn_mfma_f32_16x16x32_bf16(
              afr[mi], bfr[ni], acc[mi][ni], 0, 0, 0);
    }
  }

  const int crow = tm * BM + wr * 64 + ((lane >> 4) << 2);
  const int ccol = tn * BN + wc * 64 + frow;
  float bvv[4];
#pragma unroll
  for (int ni = 0; ni < 4; ++ni) bvv[ni] = BIAS[ccol + ni * 16];
#pragma unroll
  for (int mi = 0; mi < 4; ++mi)
#pragma unroll
    for (int ni = 0; ni < 4; ++ni) {
#pragma unroll
      for (int j = 0; j < 4; ++j) {
        OUT[(size_t)(crow + mi * 16 + j) * N + ccol + ni * 16] =
            acc[mi][ni][j] + bvv[ni];
      }
    }
}

extern "C" void kernel_launch(void* const* d_in, const int* in_sizes, int n_in,
                              void* d_out, int out_size, void* d_ws,
                              size_t ws_size, hipStream_t stream) {
  const float* x = (const float*)d_in[0];
  const int* codes = (const int*)d_in[1];
  const float* absmax = (const float*)d_in[2];
  const float* bias = (const float*)d_in[3];
  float* out = (float*)d_out;

  const int N = in_sizes[3];                    // out features
  const long long nk = (long long)in_sizes[1];  // N*K
  const int K = (int)(nk / N);
  const int M = in_sizes[0] / K;

  const size_t needA = (size_t)M * K * 2;
  const size_t needB = (size_t)N * K * 2;

  const bool big_ok = (ws_size >= needA + needB) && (M % 256 == 0) &&
                      (N % 256 == 0) && (K % 128 == 0) && (K >= 512);

  if (big_ok) {
    u16* xb = (u16*)d_ws;
    u16* wb = (u16*)((char*)d_ws + needA);
    long long nx = (long long)M * K;
    long long tot8 = (nx + nk) / 8;
    prep<<<(int)((tot8 + 255) / 256), 256, 0, stream>>>(x, codes, absmax, xb,
                                                        wb, nx, nk);
    dim3 grid((M / 256) * (N / 256)), blk(512);
    gemm32<<<grid, blk, 0, stream>>>(xb, wb, bias, out, M, N, K);
  } else if (ws_size >= needB) {
    u16* wq = (u16*)d_ws;
    dequant_w<<<(int)((nk / 8 + 255) / 256), 256, 0, stream>>>(codes, absmax,
                                                               wq, nk);
    dim3 grid((M / BM) * (N / BN)), blk(256);
    gemm_nf4<false><<<grid, blk, 0, stream>>>(x, codes, wq, absmax, bias, out,
                                              M, N, K);
  } else {
    dim3 grid((M / BM) * (N / BN)), blk(256);
    gemm_nf4<true><<<grid, blk, 0, stream>>>(x, codes, (const u16*)nullptr,
                                             absmax, bias, out, M, N, K);
  }
}

// Round 7
// 390.593 us; speedup vs baseline: 1.7226x; 1.7226x over previous
//
#include <hip/hip_runtime.h>
#include <hip/hip_bf16.h>

typedef float f32x4 __attribute__((ext_vector_type(4)));
typedef float f32x16 __attribute__((ext_vector_type(16)));
typedef short s16x8 __attribute__((ext_vector_type(8)));
typedef int i32x4 __attribute__((ext_vector_type(4)));
typedef unsigned short u16;

__constant__ float NF4_TBL[16] = {
    -1.0f, -0.6961928009986877f, -0.5250730514526367f, -0.39491748809814453f,
    -0.28444138169288635f, -0.18477343022823334f, -0.09105003625154495f, 0.0f,
    0.07958029955625534f, 0.16093020141124725f, 0.24611230194568634f,
    0.33791524171829224f, 0.44070982933044434f, 0.5626170039176941f,
    0.7229568362236023f, 1.0f};

static __device__ __forceinline__ unsigned short f2bf(float f) {
  unsigned u = __builtin_bit_cast(unsigned, f);
  u += 0x7fffu + ((u >> 16) & 1u);  // RNE
  return (unsigned short)(u >> 16);
}

static __device__ __forceinline__ void gload16(const void* g, void* l) {
  __builtin_amdgcn_global_load_lds(
      (const __attribute__((address_space(1))) unsigned*)g,
      (__attribute__((address_space(3))) unsigned*)l, 16, 0, 0);
}

// ---- prep A: X fp32 [M][K] -> bf16 k8-packed: chunk(kpack,m) 16B at
// (kpack*M + m)*8 u16.  64m x 64k tile per block, LDS transpose. ----
__global__ __launch_bounds__(256)
void prep_a(const float* __restrict__ x, u16* __restrict__ apk, int M, int K) {
  __shared__ __align__(16) char lt[8192];  // [8 kp][64 m] x 16B
  const int t = threadIdx.x;
  const int nbk = K >> 6;
  const int bm = (int)blockIdx.x / nbk;
  const int bk = (int)blockIdx.x % nbk;
  const int ml = t >> 2;
  const int kq = t & 3;
  const float* src = x + (long long)(bm * 64 + ml) * K + bk * 64 + kq * 16;
  f32x4 v0 = *(const f32x4*)src;
  f32x4 v1 = *(const f32x4*)(src + 4);
  f32x4 v2 = *(const f32x4*)(src + 8);
  f32x4 v3 = *(const f32x4*)(src + 12);
  s16x8 c0, c1;
#pragma unroll
  for (int j = 0; j < 4; ++j) {
    c0[j] = (short)f2bf(v0[j]);
    c0[j + 4] = (short)f2bf(v1[j]);
    c1[j] = (short)f2bf(v2[j]);
    c1[j + 4] = (short)f2bf(v3[j]);
  }
  *(s16x8*)(lt + (kq * 2) * 1024 + ml * 16) = c0;
  *(s16x8*)(lt + (kq * 2 + 1) * 1024 + ml * 16) = c1;
  __syncthreads();
#pragma unroll
  for (int h = 0; h < 2; ++h) {
    const int c = t + h * 256;
    const int kp = c >> 6, m = c & 63;
    s16x8 vv = *(const s16x8*)(lt + kp * 1024 + m * 16);
    *(s16x8*)(apk + ((long long)(bk * 8 + kp) * M + bm * 64 + m) * 8) = vv;
  }
}

// ---- prep W: NF4 codes -> bf16 row-major [N][K] ----
__global__ __launch_bounds__(256)
void dequant_w(const int* __restrict__ codes, const float* __restrict__ absmax,
               u16* __restrict__ wq, long long total) {
  __shared__ float lut[512];
  for (int j = threadIdx.x; j < 512; j += 256) lut[j] = NF4_TBL[j >> 5];
  __syncthreads();
  const int ln31 = threadIdx.x & 31;
  long long e = ((long long)blockIdx.x * 256 + threadIdx.x) * 8;
  if (e >= total) return;
  i32x4 c0 = *(const i32x4*)(codes + e);
  i32x4 c1 = *(const i32x4*)(codes + e + 4);
  float am = absmax[e >> 6];
  s16x8 o;
#pragma unroll
  for (int j = 0; j < 4; ++j) {
    o[j] = (short)f2bf(lut[(c0[j] << 5) + ln31] * am);
    o[j + 4] = (short)f2bf(lut[(c1[j] << 5) + ln31] * am);
  }
  *(s16x8*)(wq + e) = o;
}

// ===== main: 256x256, BK=64, 32x32x16 MFMA; A direct global->VGPR (packed),
// B via 3-slot LDS ring (96 KiB) with counted vmcnt(4); ONE barrier/K-tile.
// LDS traffic per K-tile per block: 32KB stage + 64KB read (vs 192KB before)
// -> MFMA-dominant. A-loads pipeline freely (no LDS, no barrier dependency).
#define VM0() asm volatile("s_waitcnt vmcnt(0)" ::: "memory")
#define VM4() asm volatile("s_waitcnt vmcnt(4)" ::: "memory")
#define SB0() __builtin_amdgcn_sched_barrier(0)

__global__ __launch_bounds__(512, 2)
void gemma(const u16* __restrict__ APK, const u16* __restrict__ B,
           const float* __restrict__ BIAS, float* __restrict__ OUT,
           int M, int N, int K) {
  __shared__ __align__(16) char lds[98304];  // 3 x 32KB B slots

  const int tid = threadIdx.x;
  const int lane = tid & 63;
  const int wid = tid >> 6;
  const int wr = wid >> 2;  // 0..1 : M-half (128 rows)
  const int wc = wid & 3;   // 0..3 : N-quarter (64 cols)

  int nwg = (int)gridDim.x;
  int b = (int)blockIdx.x;
  if ((nwg & 7) == 0) b = (b & 7) * (nwg >> 3) + (b >> 3);  // XCD swizzle
  const int ntm = M / 256;
  const int tn = b / ntm;  // column-major tile order: B-panel L2 reuse
  const int tm = b % ntm;

  const long long K2 = (long long)K * 2;
  // ---- B staging (pre-swizzled source; key = (row&7)^((row>>3)&3)) ----
  const int trow = tid >> 3;
  const int skey = (trow & 7) ^ ((trow >> 3) & 3);
  const char* sgB =
      (const char*)B + ((long long)(tn * 256 + trow)) * K2 +
      (((tid & 7) ^ skey) << 4);
  const int sldso = tid * 16;
  auto stB = [&](int kt, int slot) {
    char* d = lds + slot * 32768 + sldso;
#pragma unroll
    for (int g = 0; g < 4; ++g)
      gload16(sgB + (long long)(g * 64) * K2 + (long long)kt * 128,
              d + g * 8192);
  };

  // ---- fragment addressing ----
  const int l31 = lane & 31;
  const int lk = lane >> 5;
  const int rkey = (l31 & 7) ^ ((l31 >> 3) & 3);
  int bslot[4];
#pragma unroll
  for (int s = 0; s < 4; ++s) bslot[s] = ((s * 2 + lk) ^ rkey) << 4;

  // A lane base in packed layout: (kpack*M + m)*8 u16; kpack = kt*8+s*2+lk
  const long long Mll = (long long)M;
  const u16* aLane =
      APK + ((long long)lk * Mll + tm * 256 + wr * 128 + l31) * 8;
  const long long KT_ST = 64LL * Mll;  // u16 per K-tile (8 kpacks)
  const long long S_ST = 16LL * Mll;   // u16 per k-slice (2 kpacks)

  f32x16 acc[4][2];
  {
    f32x16 zz;
#pragma unroll
    for (int r = 0; r < 16; ++r) zz[r] = 0.f;
#pragma unroll
    for (int m_ = 0; m_ < 4; ++m_)
#pragma unroll
      for (int n_ = 0; n_ < 2; ++n_) acc[m_][n_] = zz;
  }

  const int nkt = K / 64;
  // prologue: stage tiles 0,1 into slots 0,1
  stB(0, 0);
  stB(1, 1);
  int cur = 0, stg = 2;

  for (int kt = 0; kt < nkt; ++kt) {
    // gate: B-stage(kt) retired (the 4 newest gloads = stage kt+1 may fly)
    if (kt + 1 < nkt)
      VM4();
    else
      VM0();
    __builtin_amdgcn_s_barrier();
    SB0();

    // A fragments for THIS tile (first s-slice latency hides under ds path)
    s16x8 ar[4][4];
    const u16* ab = aLane + (long long)kt * KT_ST;
#pragma unroll
    for (int s = 0; s < 4; ++s)
#pragma unroll
      for (int mp = 0; mp < 4; ++mp)
        ar[s][mp] = *(const s16x8*)(ab + s * S_ST + mp * 256);

    if (kt + 2 < nkt) stB(kt + 2, stg);

    // B fragments from LDS
    const char* bp = lds + cur * 32768 + (wc * 64 + l31) * 128;
    s16x8 bf[2][4];
#pragma unroll
    for (int s = 0; s < 4; ++s) {
      bf[0][s] = *(const s16x8*)(bp + bslot[s]);
      bf[1][s] = *(const s16x8*)(bp + 4096 + bslot[s]);
    }
    asm volatile("s_waitcnt lgkmcnt(0)" ::: "memory");
    SB0();

    __builtin_amdgcn_s_setprio(1);
#pragma unroll
    for (int s = 0; s < 4; ++s)
#pragma unroll
      for (int mp = 0; mp < 4; ++mp)
#pragma unroll
        for (int n_ = 0; n_ < 2; ++n_)
          acc[mp][n_] = __builtin_amdgcn_mfma_f32_32x32x16_bf16(
              ar[s][mp], bf[n_][s], acc[mp][n_], 0, 0, 0);
    __builtin_amdgcn_s_setprio(0);

    cur = (cur == 2) ? 0 : cur + 1;
    stg = (stg == 2) ? 0 : stg + 1;
  }

  // epilogue: 32x32 C/D layout col=lane&31, row=(r&3)+8*(r>>2)+4*(lane>>5)
  const int ocol = tn * 256 + wc * 64 + l31;
  const int orow0 = tm * 256 + wr * 128 + 4 * lk;
  const float bv0 = BIAS[ocol];
  const float bv1 = BIAS[ocol + 32];
#pragma unroll
  for (int m_ = 0; m_ < 4; ++m_)
#pragma unroll
    for (int n_ = 0; n_ < 2; ++n_) {
      const float bb = n_ ? bv1 : bv0;
#pragma unroll
      for (int r = 0; r < 16; ++r) {
        const int row = orow0 + m_ * 32 + (r & 3) + 8 * (r >> 2);
        OUT[(long long)row * N + ocol + n_ * 32] = acc[m_][n_][r] + bb;
      }
    }
}

// ---------------- fallback: 128x128 reg-staged kernel ----------------
#define BM 128
#define BN 128
#define BK 64

template <bool FUSED>
static __device__ __forceinline__ void stage_load(
    const float* __restrict__ ap0, const int* __restrict__ cp0,
    const u16* __restrict__ wp0, const float* __restrict__ am0, int K, int kt,
    f32x4 (&ar)[4][2], i32x4 (&cr)[4][2], s16x8 (&wreg)[4], float (&amr)[4]) {
  const size_t ko = (size_t)kt * BK;
#pragma unroll
  for (int p = 0; p < 4; ++p) {
    const float* ap = ap0 + (size_t)(p * 32) * K + ko;
    ar[p][0] = *(const f32x4*)ap;
    ar[p][1] = *(const f32x4*)(ap + 4);
    if constexpr (FUSED) {
      const int* cp = cp0 + (size_t)(p * 32) * K + ko;
      cr[p][0] = *(const i32x4*)cp;
      cr[p][1] = *(const i32x4*)(cp + 4);
      amr[p] = am0[p * 32 * (K >> 6) + kt];
    } else {
      wreg[p] = *(const s16x8*)(wp0 + (size_t)(p * 32) * K + ko);
    }
  }
}

template <bool FUSED>
__global__ __launch_bounds__(256, 2)
void gemm_nf4(const float* __restrict__ X, const int* __restrict__ CODES,
              const u16* __restrict__ WQ, const float* __restrict__ AMAX,
              const float* __restrict__ BIAS, float* __restrict__ OUT,
              int M, int N, int K) {
  __shared__ short As[BM * BK];
  __shared__ short Bs[BN * BK];
  __shared__ float lut[512];

  const int tid = threadIdx.x;
  const int lane = tid & 63;
  const int wid = tid >> 6;

  if constexpr (FUSED) {
#pragma unroll
    for (int j = 0; j < 2; ++j) {
      int idx = tid + j * 256;
      lut[idx] = NF4_TBL[idx >> 5];
    }
  }

  int nwg = (int)gridDim.x;
  int b = (int)blockIdx.x;
  if ((nwg & 7) == 0) b = (b & 7) * (nwg >> 3) + (b >> 3);
  const int ntn = N / BN;
  const int tm = b / ntn;
  const int tn = b % ntn;

  const int srow = tid >> 3;
  const int scol = (tid & 7) * 8;
  const int ln31 = tid & 31;
  const int swz_w = (srow & 7) << 4;

  const float* ap0 = X + (size_t)(tm * BM + srow) * K + scol;
  const int* cp0 = CODES + (size_t)(tn * BN + srow) * K + scol;
  const u16* wp0 = WQ + (size_t)(tn * BN + srow) * K + scol;
  const float* am0 = AMAX + (size_t)(tn * BN + srow) * (K >> 6);

  f32x4 ar[4][2];
  i32x4 cr[4][2];
  s16x8 wreg[4];
  float amr[4];

  f32x4 acc[4][4];
#pragma unroll
  for (int i = 0; i < 4; ++i)
#pragma unroll
    for (int j = 0; j < 4; ++j) {
      f32x4 z = {0.f, 0.f, 0.f, 0.f};
      acc[i][j] = z;
    }

  const int wr = wid >> 1;
  const int wc = wid & 1;
  const int frow = lane & 15;
  const int fcolb = (lane >> 4) * 16;
  const int arow = wr * 64 + frow;
  const int brow = wc * 64 + frow;
  const int aswz = (arow & 7) << 4;
  const int bswz = (brow & 7) << 4;
  const char* asp = (const char*)As + arow * 128;
  const char* bsp = (const char*)Bs + brow * 128;
  char* awp = (char*)As + srow * 128 + ((scol * 2) ^ swz_w);
  char* bwp = (char*)Bs + srow * 128 + ((scol * 2) ^ swz_w);

  const int nkt = K / BK;
  stage_load<FUSED>(ap0, cp0, wp0, am0, K, 0, ar, cr, wreg, amr);

  for (int kt = 0; kt < nkt; ++kt) {
    __syncthreads();
#pragma unroll
    for (int p = 0; p < 4; ++p) {
      s16x8 av;
#pragma unroll
      for (int j = 0; j < 4; ++j) {
        av[j] = (short)f2bf(ar[p][0][j]);
        av[j + 4] = (short)f2bf(ar[p][1][j]);
      }
      *(s16x8*)(awp + p * 32 * 128) = av;
      s16x8 bv;
      if constexpr (FUSED) {
        float am = amr[p];
#pragma unroll
        for (int j = 0; j < 4; ++j) {
          bv[j] = (short)f2bf(lut[(cr[p][0][j] << 5) + ln31] * am);
          bv[j + 4] = (short)f2bf(lut[(cr[p][1][j] << 5) + ln31] * am);
        }
      } else {
        bv = wreg[p];
      }
      *(s16x8*)(bwp + p * 32 * 128) = bv;
    }
    __syncthreads();

    if (kt + 1 < nkt)
      stage_load<FUSED>(ap0, cp0, wp0, am0, K, kt + 1, ar, cr, wreg, amr);

#pragma unroll
    for (int kk = 0; kk < 2; ++kk) {
      const int qa = (fcolb | (kk << 6)) ^ aswz;
      const int qb = (fcolb | (kk << 6)) ^ bswz;
      s16x8 afr[4], bfr[4];
#pragma unroll
      for (int mi = 0; mi < 4; ++mi)
        afr[mi] = *(const s16x8*)(asp + mi * 2048 + qa);
#pragma unroll
      for (int ni = 0; ni < 4; ++ni)
        bfr[ni] = *(const s16x8*)(bsp + ni * 2048 + qb);
#pragma unroll
      for (int mi = 0; mi < 4; ++mi)
#pragma unroll
        for (int ni = 0; ni < 4; ++ni)
          acc[mi][ni] = __builtin_amdgcn_mfma_f32_16x16x32_bf16(
              afr[mi], bfr[ni], acc[mi][ni], 0, 0, 0);
    }
  }

  const int crow = tm * BM + wr * 64 + ((lane >> 4) << 2);
  const int ccol = tn * BN + wc * 64 + frow;
  float bvv[4];
#pragma unroll
  for (int ni = 0; ni < 4; ++ni) bvv[ni] = BIAS[ccol + ni * 16];
#pragma unroll
  for (int mi = 0; mi < 4; ++mi)
#pragma unroll
    for (int ni = 0; ni < 4; ++ni) {
#pragma unroll
      for (int j = 0; j < 4; ++j) {
        OUT[(size_t)(crow + mi * 16 + j) * N + ccol + ni * 16] =
            acc[mi][ni][j] + bvv[ni];
      }
    }
}

extern "C" void kernel_launch(void* const* d_in, const int* in_sizes, int n_in,
                              void* d_out, int out_size, void* d_ws,
                              size_t ws_size, hipStream_t stream) {
  const float* x = (const float*)d_in[0];
  const int* codes = (const int*)d_in[1];
  const float* absmax = (const float*)d_in[2];
  const float* bias = (const float*)d_in[3];
  float* out = (float*)d_out;

  const int N = in_sizes[3];                    // out features
  const long long nk = (long long)in_sizes[1];  // N*K
  const int K = (int)(nk / N);
  const int M = in_sizes[0] / K;

  const size_t needA = (size_t)M * K * 2;
  const size_t needB = (size_t)N * K * 2;

  const bool big_ok = (ws_size >= needA + needB) && (M % 256 == 0) &&
                      (N % 256 == 0) && (K % 128 == 0) && (K >= 512);

  if (big_ok) {
    u16* apk = (u16*)d_ws;
    u16* wb = (u16*)((char*)d_ws + needA);
    prep_a<<<(M / 64) * (K / 64), 256, 0, stream>>>(x, apk, M, K);
    dequant_w<<<(int)((nk / 8 + 255) / 256), 256, 0, stream>>>(codes, absmax,
                                                               wb, nk);
    dim3 grid((M / 256) * (N / 256)), blk(512);
    gemma<<<grid, blk, 0, stream>>>(apk, wb, bias, out, M, N, K);
  } else if (ws_size >= needB) {
    u16* wq = (u16*)d_ws;
    dequant_w<<<(int)((nk / 8 + 255) / 256), 256, 0, stream>>>(codes, absmax,
                                                               wq, nk);
    dim3 grid((M / BM) * (N / BN)), blk(256);
    gemm_nf4<false><<<grid, blk, 0, stream>>>(x, codes, wq, absmax, bias, out,
                                              M, N, K);
  } else {
    dim3 grid((M / BM) * (N / BN)), blk(256);
    gemm_nf4<true><<<grid, blk, 0, stream>>>(x, codes, (const u16*)nullptr,
                                             absmax, bias, out, M, N, K);
  }
}

// Round 8
// 295.068 us; speedup vs baseline: 2.2802x; 1.3237x over previous
//
#include <hip/hip_runtime.h>
#include <hip/hip_bf16.h>

typedef float f32x4 __attribute__((ext_vector_type(4)));
typedef float f32x16 __attribute__((ext_vector_type(16)));
typedef short s16x8 __attribute__((ext_vector_type(8)));
typedef int i32x4 __attribute__((ext_vector_type(4)));
typedef unsigned short u16;

__constant__ float NF4_TBL[16] = {
    -1.0f, -0.6961928009986877f, -0.5250730514526367f, -0.39491748809814453f,
    -0.28444138169288635f, -0.18477343022823334f, -0.09105003625154495f, 0.0f,
    0.07958029955625534f, 0.16093020141124725f, 0.24611230194568634f,
    0.33791524171829224f, 0.44070982933044434f, 0.5626170039176941f,
    0.7229568362236023f, 1.0f};

static __device__ __forceinline__ unsigned short f2bf(float f) {
  unsigned u = __builtin_bit_cast(unsigned, f);
  u += 0x7fffu + ((u >> 16) & 1u);  // RNE
  return (unsigned short)(u >> 16);
}

static __device__ __forceinline__ void gload16(const void* g, void* l) {
  __builtin_amdgcn_global_load_lds(
      (const __attribute__((address_space(1))) unsigned*)g,
      (__attribute__((address_space(3))) unsigned*)l, 16, 0, 0);
}

// ---------------- fused prep: X fp32->bf16 and NF4 W->bf16 ----------------
__global__ __launch_bounds__(256)
void prep(const float* __restrict__ x, const int* __restrict__ codes,
          const float* __restrict__ absmax, u16* __restrict__ xb,
          u16* __restrict__ wb, long long nx, long long nk) {
  __shared__ float lut[512];
  for (int j = threadIdx.x; j < 512; j += 256) lut[j] = NF4_TBL[j >> 5];
  __syncthreads();
  long long i = ((long long)blockIdx.x * 256 + threadIdx.x) * 8;
  if (i < nx) {
    f32x4 a = *(const f32x4*)(x + i);
    f32x4 b = *(const f32x4*)(x + i + 4);
    s16x8 o;
#pragma unroll
    for (int j = 0; j < 4; ++j) {
      o[j] = (short)f2bf(a[j]);
      o[j + 4] = (short)f2bf(b[j]);
    }
    *(s16x8*)(xb + i) = o;
  } else {
    long long e = i - nx;
    if (e < nk) {
      const int ln31 = threadIdx.x & 31;
      i32x4 c0 = *(const i32x4*)(codes + e);
      i32x4 c1 = *(const i32x4*)(codes + e + 4);
      float am = absmax[e >> 6];
      s16x8 o;
#pragma unroll
      for (int j = 0; j < 4; ++j) {
        o[j] = (short)f2bf(lut[(c0[j] << 5) + ln31] * am);
        o[j + 4] = (short)f2bf(lut[(c1[j] << 5) + ln31] * am);
      }
      *(s16x8*)(wb + e) = o;
    }
  }
}

// standalone dequant for the mid fallback path
__global__ __launch_bounds__(256)
void dequant_w(const int* __restrict__ codes, const float* __restrict__ absmax,
               u16* __restrict__ wq, long long total) {
  __shared__ float lut[512];
  for (int j = threadIdx.x; j < 512; j += 256) lut[j] = NF4_TBL[j >> 5];
  __syncthreads();
  const int ln31 = threadIdx.x & 31;
  long long e = ((long long)blockIdx.x * 256 + threadIdx.x) * 8;
  if (e >= total) return;
  i32x4 c0 = *(const i32x4*)(codes + e);
  i32x4 c1 = *(const i32x4*)(codes + e + 4);
  float am = absmax[e >> 6];
  s16x8 o;
#pragma unroll
  for (int j = 0; j < 4; ++j) {
    o[j] = (short)f2bf(lut[(c0[j] << 5) + ln31] * am);
    o[j + 4] = (short)f2bf(lut[(c1[j] << 5) + ln31] * am);
  }
  *(s16x8*)(wq + e) = o;
}

// ===== main: 256x256 bf16 GEMM, BK=64, 8-phase, 32x32x16 =====
// Round-8: (1) balanced 8/4/8/4 read phases -- B-h0 reads moved one phase
// earlier into the VM6-gated phases (p4 reads B0 of kt+1, p8 reads B0 of
// kt+2, prologue pre-reads B0 of kt0); bnP/bnQ lifetime chain keeps B at 2
// live sets (32 VGPR) = same footprint as R5. (2) ONE barrier per phase
// (SYNC_OUT dropped): reads issue pre-barrier, retire at that phase's
// lgkmcnt(0) before the wave reaches the next barrier; earliest re-stage of
// any region is >=1 barrier later (checked per region), so <=1-phase drift
// cannot create an LDS WAR hazard.
#define VM6() asm volatile("s_waitcnt vmcnt(6)" ::: "memory")
#define VM0() asm volatile("s_waitcnt vmcnt(0)" ::: "memory")
#define SB0() __builtin_amdgcn_sched_barrier(0)
#define SYNC1()                                              \
  do {                                                       \
    __builtin_amdgcn_s_barrier();                            \
    asm volatile("s_waitcnt lgkmcnt(0)" ::: "memory");       \
    __builtin_amdgcn_sched_barrier(0);                       \
  } while (0)

// one phase's MFMA cluster: 2 m-tiles x 4 k-steps into acc[MB..MB+1][NB]
#define MM32(AV, BV, MB, NB)                                               \
  do {                                                                     \
    __builtin_amdgcn_s_setprio(1);                                         \
    _Pragma("unroll") for (int s_ = 0; s_ < 4; ++s_)                       \
    _Pragma("unroll") for (int mp_ = 0; mp_ < 2; ++mp_)                    \
        acc[(MB) + mp_][NB] = __builtin_amdgcn_mfma_f32_32x32x16_bf16(     \
            AV[mp_][s_], BV[s_], acc[(MB) + mp_][NB], 0, 0, 0);            \
    __builtin_amdgcn_s_setprio(0);                                         \
  } while (0)

__global__ __launch_bounds__(512, 2)
void gemm32(const u16* __restrict__ A, const u16* __restrict__ B,
            const float* __restrict__ BIAS, float* __restrict__ OUT,
            int M, int N, int K) {
  __shared__ __align__(16) char lds[131072];  // 2 buf x (A 32K + B 32K)

  const int tid = threadIdx.x;
  const int lane = tid & 63;
  const int wid = tid >> 6;
  const int wr = wid >> 2;  // 0..1 : M-half (128 rows)
  const int wc = wid & 3;   // 0..3 : N-quarter (64 cols)

  int nwg = (int)gridDim.x;
  int b = (int)blockIdx.x;
  if ((nwg & 7) == 0) b = (b & 7) * (nwg >> 3) + (b >> 3);  // XCD swizzle
  const int ntm = M / 256;
  const int tn = b / ntm;  // column-major tile order: B-panel L2 reuse
  const int tm = b % ntm;

  const long long K2 = (long long)K * 2;
  // ---- staging source (pre-swizzled 16B slot within 128B K-row) ----
  const int trow = tid >> 3;
  const int skey = (trow & 7) ^ ((trow >> 3) & 3);
  const int scol = ((tid & 7) ^ skey) << 4;
  const char* sgA =
      (const char*)A + ((long long)tm * 256 + trow) * K2 + scol;
  const char* sgB = (const char*)B +
                    ((long long)tn * 256 + (tid >> 8) * 64 + (trow & 31)) * K2 +
                    scol;
  const int sldso = tid * 16;

  // stage one half-tile (2 x gload16)
  auto stA = [&](int kt, int buf, int h) {
    char* d = lds + buf * 65536 + h * 16384 + sldso;
    const char* s = sgA + (long long)h * 64 * K2 + (long long)kt * 128;
    gload16(s, d);
    gload16(s + 128 * K2, d + 8192);
  };
  auto stB = [&](int kt, int buf, int h) {
    char* d = lds + buf * 65536 + 32768 + h * 16384 + sldso;
    const char* s = sgB + (long long)h * 32 * K2 + (long long)kt * 128;
    gload16(s, d);
    gload16(s + 128 * K2, d + 8192);
  };

  // ---- fragment read addressing (32x32x16: A row=lane&31, k=(lane>>5)*8+j)
  const int l31 = lane & 31;
  const int lk = lane >> 5;
  const int rkey = (l31 & 7) ^ ((l31 >> 3) & 3);
  int aslot[4];
#pragma unroll
  for (int s_ = 0; s_ < 4; ++s_) aslot[s_] = ((s_ * 2 + lk) ^ rkey) << 4;

  s16x8 aa[2][4], bnP[4], bnQ[4];
  auto rdA32 = [&](int buf, int h) {
    const char* p = lds + buf * 65536 + h * 16384 + (wr * 64 + l31) * 128;
#pragma unroll
    for (int mp_ = 0; mp_ < 2; ++mp_)
#pragma unroll
      for (int s_ = 0; s_ < 4; ++s_)
        aa[mp_][s_] = *(const s16x8*)(p + mp_ * 4096 + aslot[s_]);
  };
  auto rdB32 = [&](int buf, int h, s16x8(&bv)[4]) {
    const char* p =
        lds + buf * 65536 + 32768 + h * 16384 + (wc * 32 + l31) * 128;
#pragma unroll
    for (int s_ = 0; s_ < 4; ++s_) bv[s_] = *(const s16x8*)(p + aslot[s_]);
  };

  f32x16 acc[4][2];
  {
    f32x16 zz;
#pragma unroll
    for (int r = 0; r < 16; ++r) zz[r] = 0.f;
#pragma unroll
    for (int m_ = 0; m_ < 4; ++m_)
#pragma unroll
      for (int n_ = 0; n_ < 2; ++n_) acc[m_][n_] = zz;
  }

  const int nkt = K / 64;
  const int nit = nkt / 2;

  // prologue: buf0 <- kt0 (full), buf1 <- kt1 (all but A-half-1)
  stB(0, 0, 0);
  stA(0, 0, 0);
  stB(0, 0, 1);
  stA(0, 0, 1);
  stB(1, 1, 0);
  stA(1, 1, 0);
  stB(1, 1, 1);
  VM6();  // buf0 complete; buf1's newest 3 stages may stay in flight
  __builtin_amdgcn_s_barrier();
  rdB32(0, 0, bnP);  // pre-read B0 of kt0 (drains at p1's lgkmcnt(0))

  for (int it = 0; it < nit; ++it) {
    const int kt = 2 * it;
    const bool full = (it + 1 < nit);
    SB0();
    // ---- p1: Q00 = (m0-1, n0) of kt ---- reads A0 (8)
    rdA32(0, 0);
    stA(kt + 1, 1, 1);  // buf1.A-h1 <- kt+1 (read at p7)
    SYNC1();
    MM32(aa, bnP, 0, 0);
    // ---- p2: Q01 ---- reads B1 kt (4)
    rdB32(0, 1, bnQ);
    if (full) stB(kt + 2, 0, 0);
    SYNC1();
    MM32(aa, bnQ, 0, 1);
    // ---- p3: Q21 ---- reads A1 kt (8)
    rdA32(0, 1);
    if (full) stA(kt + 2, 0, 0);
    SYNC1();
    MM32(aa, bnQ, 2, 1);
    // ---- p4: Q20 ---- VM6 gate; reads B0 of kt+1 (4, post-VM6)
    if (full) {
      stB(kt + 2, 0, 1);
      VM6();
    } else {
      VM0();
    }
    rdB32(1, 0, bnQ);  // buf1-B-h0 staged p6-prev, retired by this gate
    SYNC1();
    MM32(aa, bnP, 2, 0);  // bnP = B0 of kt
    // ---- p5: Q00' of kt+1 ---- reads A0' (8)
    rdA32(1, 0);
    if (full) stA(kt + 2, 0, 1);
    SYNC1();
    MM32(aa, bnQ, 0, 0);
    // ---- p6: Q01' ---- reads B1' (4)
    rdB32(1, 1, bnP);  // bnP last used p4
    if (full) stB(kt + 3, 1, 0);
    SYNC1();
    MM32(aa, bnP, 0, 1);
    // ---- p7: Q21' ---- reads A1' (8)
    rdA32(1, 1);
    if (full) stA(kt + 3, 1, 0);
    SYNC1();
    MM32(aa, bnP, 2, 1);
    // ---- p8: Q20' ---- VM6 gate; reads B0 of kt+2 (4, post-VM6)
    if (full) {
      stB(kt + 3, 1, 1);
      VM6();
      rdB32(0, 0, bnP);  // buf0-B-h0 staged p2, retired by this VM6
    }
    SYNC1();
    MM32(aa, bnQ, 2, 0);  // bnQ = B0 of kt+1
  }

  // epilogue: 32x32 C/D layout col=lane&31, row=(r&3)+8*(r>>2)+4*(lane>>5)
  const int ocol = tn * 256 + wc * 64 + l31;
  const int orow0 = tm * 256 + wr * 128 + 4 * lk;
  const float bv0 = BIAS[ocol];
  const float bv1 = BIAS[ocol + 32];
#pragma unroll
  for (int m_ = 0; m_ < 4; ++m_)
#pragma unroll
    for (int n_ = 0; n_ < 2; ++n_) {
      const float bb = n_ ? bv1 : bv0;
#pragma unroll
      for (int r = 0; r < 16; ++r) {
        const int row = orow0 + m_ * 32 + (r & 3) + 8 * (r >> 2);
        OUT[(long long)row * N + ocol + n_ * 32] = acc[m_][n_][r] + bb;
      }
    }
}

// ---------------- fallback: 128x128 reg-staged kernel ----------------
#define BM 128
#define BN 128
#define BK 64

template <bool FUSED>
static __device__ __forceinline__ void stage_load(
    const float* __restrict__ ap0, const int* __restrict__ cp0,
    const u16* __restrict__ wp0, const float* __restrict__ am0, int K, int kt,
    f32x4 (&ar)[4][2], i32x4 (&cr)[4][2], s16x8 (&wreg)[4], float (&amr)[4]) {
  const size_t ko = (size_t)kt * BK;
#pragma unroll
  for (int p = 0; p < 4; ++p) {
    const float* ap = ap0 + (size_t)(p * 32) * K + ko;
    ar[p][0] = *(const f32x4*)ap;
    ar[p][1] = *(const f32x4*)(ap + 4);
    if constexpr (FUSED) {
      const int* cp = cp0 + (size_t)(p * 32) * K + ko;
      cr[p][0] = *(const i32x4*)cp;
      cr[p][1] = *(const i32x4*)(cp + 4);
      amr[p] = am0[p * 32 * (K >> 6) + kt];
    } else {
      wreg[p] = *(const s16x8*)(wp0 + (size_t)(p * 32) * K + ko);
    }
  }
}

template <bool FUSED>
__global__ __launch_bounds__(256, 2)
void gemm_nf4(const float* __restrict__ X, const int* __restrict__ CODES,
              const u16* __restrict__ WQ, const float* __restrict__ AMAX,
              const float* __restrict__ BIAS, float* __restrict__ OUT,
              int M, int N, int K) {
  __shared__ short As[BM * BK];
  __shared__ short Bs[BN * BK];
  __shared__ float lut[512];

  const int tid = threadIdx.x;
  const int lane = tid & 63;
  const int wid = tid >> 6;

  if constexpr (FUSED) {
#pragma unroll
    for (int j = 0; j < 2; ++j) {
      int idx = tid + j * 256;
      lut[idx] = NF4_TBL[idx >> 5];
    }
  }

  int nwg = (int)gridDim.x;
  int b = (int)blockIdx.x;
  if ((nwg & 7) == 0) b = (b & 7) * (nwg >> 3) + (b >> 3);
  const int ntn = N / BN;
  const int tm = b / ntn;
  const int tn = b % ntn;

  const int srow = tid >> 3;
  const int scol = (tid & 7) * 8;
  const int ln31 = tid & 31;
  const int swz_w = (srow & 7) << 4;

  const float* ap0 = X + (size_t)(tm * BM + srow) * K + scol;
  const int* cp0 = CODES + (size_t)(tn * BN + srow) * K + scol;
  const u16* wp0 = WQ + (size_t)(tn * BN + srow) * K + scol;
  const float* am0 = AMAX + (size_t)(tn * BN + srow) * (K >> 6);

  f32x4 ar[4][2];
  i32x4 cr[4][2];
  s16x8 wreg[4];
  float amr[4];

  f32x4 acc[4][4];
#pragma unroll
  for (int i = 0; i < 4; ++i)
#pragma unroll
    for (int j = 0; j < 4; ++j) {
      f32x4 z = {0.f, 0.f, 0.f, 0.f};
      acc[i][j] = z;
    }

  const int wr = wid >> 1;
  const int wc = wid & 1;
  const int frow = lane & 15;
  const int fcolb = (lane >> 4) * 16;
  const int arow = wr * 64 + frow;
  const int brow = wc * 64 + frow;
  const int aswz = (arow & 7) << 4;
  const int bswz = (brow & 7) << 4;
  const char* asp = (const char*)As + arow * 128;
  const char* bsp = (const char*)Bs + brow * 128;
  char* awp = (char*)As + srow * 128 + ((scol * 2) ^ swz_w);
  char* bwp = (char*)Bs + srow * 128 + ((scol * 2) ^ swz_w);

  const int nkt = K / BK;
  stage_load<FUSED>(ap0, cp0, wp0, am0, K, 0, ar, cr, wreg, amr);

  for (int kt = 0; kt < nkt; ++kt) {
    __syncthreads();
#pragma unroll
    for (int p = 0; p < 4; ++p) {
      s16x8 av;
#pragma unroll
      for (int j = 0; j < 4; ++j) {
        av[j] = (short)f2bf(ar[p][0][j]);
        av[j + 4] = (short)f2bf(ar[p][1][j]);
      }
      *(s16x8*)(awp + p * 32 * 128) = av;
      s16x8 bv;
      if constexpr (FUSED) {
        float am = amr[p];
#pragma unroll
        for (int j = 0; j < 4; ++j) {
          bv[j] = (short)f2bf(lut[(cr[p][0][j] << 5) + ln31] * am);
          bv[j + 4] = (short)f2bf(lut[(cr[p][1][j] << 5) + ln31] * am);
        }
      } else {
        bv = wreg[p];
      }
      *(s16x8*)(bwp + p * 32 * 128) = bv;
    }
    __syncthreads();

    if (kt + 1 < nkt)
      stage_load<FUSED>(ap0, cp0, wp0, am0, K, kt + 1, ar, cr, wreg, amr);

#pragma unroll
    for (int kk = 0; kk < 2; ++kk) {
      const int qa = (fcolb | (kk << 6)) ^ aswz;
      const int qb = (fcolb | (kk << 6)) ^ bswz;
      s16x8 afr[4], bfr[4];
#pragma unroll
      for (int mi = 0; mi < 4; ++mi)
        afr[mi] = *(const s16x8*)(asp + mi * 2048 + qa);
#pragma unroll
      for (int ni = 0; ni < 4; ++ni)
        bfr[ni] = *(const s16x8*)(bsp + ni * 2048 + qb);
#pragma unroll
      for (int mi = 0; mi < 4; ++mi)
#pragma unroll
        for (int ni = 0; ni < 4; ++ni)
          acc[mi][ni] = __builtin_amdgcn_mfma_f32_16x16x32_bf16(
              afr[mi], bfr[ni], acc[mi][ni], 0, 0, 0);
    }
  }

  const int crow = tm * BM + wr * 64 + ((lane >> 4) << 2);
  const int ccol = tn * BN + wc * 64 + frow;
  float bvv[4];
#pragma unroll
  for (int ni = 0; ni < 4; ++ni) bvv[ni] = BIAS[ccol + ni * 16];
#pragma unroll
  for (int mi = 0; mi < 4; ++mi)
#pragma unroll
    for (int ni = 0; ni < 4; ++ni) {
#pragma unroll
      for (int j = 0; j < 4; ++j) {
        OUT[(size_t)(crow + mi * 16 + j) * N + ccol + ni * 16] =
            acc[mi][ni][j] + bvv[ni];
      }
    }
}

extern "C" void kernel_launch(void* const* d_in, const int* in_sizes, int n_in,
                              void* d_out, int out_size, void* d_ws,
                              size_t ws_size, hipStream_t stream) {
  const float* x = (const float*)d_in[0];
  const int* codes = (const int*)d_in[1];
  const float* absmax = (const float*)d_in[2];
  const float* bias = (const float*)d_in[3];
  float* out = (float*)d_out;

  const int N = in_sizes[3];                    // out features
  const long long nk = (long long)in_sizes[1];  // N*K
  const int K = (int)(nk / N);
  const int M = in_sizes[0] / K;

  const size_t needA = (size_t)M * K * 2;
  const size_t needB = (size_t)N * K * 2;

  const bool big_ok = (ws_size >= needA + needB) && (M % 256 == 0) &&
                      (N % 256 == 0) && (K % 128 == 0) && (K >= 512);

  if (big_ok) {
    u16* xb = (u16*)d_ws;
    u16* wb = (u16*)((char*)d_ws + needA);
    long long nx = (long long)M * K;
    long long tot8 = (nx + nk) / 8;
    prep<<<(int)((tot8 + 255) / 256), 256, 0, stream>>>(x, codes, absmax, xb,
                                                        wb, nx, nk);
    dim3 grid((M / 256) * (N / 256)), blk(512);
    gemm32<<<grid, blk, 0, stream>>>(xb, wb, bias, out, M, N, K);
  } else if (ws_size >= needB) {
    u16* wq = (u16*)d_ws;
    dequant_w<<<(int)((nk / 8 + 255) / 256), 256, 0, stream>>>(codes, absmax,
                                                               wq, nk);
    dim3 grid((M / BM) * (N / BN)), blk(256);
    gemm_nf4<false><<<grid, blk, 0, stream>>>(x, codes, wq, absmax, bias, out,
                                              M, N, K);
  } else {
    dim3 grid((M / BM) * (N / BN)), blk(256);
    gemm_nf4<true><<<grid, blk, 0, stream>>>(x, codes, (const u16*)nullptr,
                                             absmax, bias, out, M, N, K);
  }
}